// Round 10
// baseline (1354.348 us; speedup 1.0000x reference)
//
#include <hip/hip_runtime.h>
#include <hip/hip_bf16.h>

#define HD   1024
#define G4   4096
#define CND  64
#define LAT  256
#define VOC  32000
#define TT   256
#define ZCN  320    // LAT + CND
#define NSEQ 64     // seq WGs
#define NWKR 160    // worker WGs
#define THR  512
#define DEC0 301u   // decoder h version base (encoder uses 1..257)
#define WCH  132    // LDS chunk stride (floats)
#define LDT  40     // gemm LDS tile row stride (ushorts)

typedef unsigned long long u64;
typedef __attribute__((ext_vector_type(8))) short short8;
typedef __attribute__((ext_vector_type(4))) float f32x4;

__device__ __forceinline__ float sig_f(float x) {
    return 1.0f / (1.0f + __expf(-x));
}
__device__ __forceinline__ float tanh_f(float x) {
    float e = __expf(2.0f * x);
    return 1.0f - 2.0f / (e + 1.0f);
}
__device__ __forceinline__ u64 al64(const u64* p) {
    return __hip_atomic_load((u64*)p, __ATOMIC_RELAXED, __HIP_MEMORY_SCOPE_AGENT);
}
__device__ __forceinline__ void as64(u64* p, u64 v) {
    __hip_atomic_store(p, v, __ATOMIC_RELAXED, __HIP_MEMORY_SCOPE_AGENT);
}
__device__ __forceinline__ u64 packhv(float h, unsigned tag) {
    return ((u64)tag << 32) | (u64)__float_as_uint(h);
}
__device__ __forceinline__ float lo_f(u64 e) {
    return __uint_as_float((unsigned)e);
}

// ===========================================================================
// 3xBF16-split helpers (proven rounds 5-9)
// ===========================================================================
__device__ __forceinline__ void cvt2(float x, ushort& h, ushort& l)
{
    unsigned u = __float_as_uint(x);
    h = (ushort)(u >> 16);
    float hif = __uint_as_float(u & 0xffff0000u);
    l = (ushort)(__float_as_uint(x - hif) >> 16);
}
__device__ __forceinline__ unsigned pk(ushort a, ushort b)
{
    return (unsigned)a | ((unsigned)b << 16);
}
__device__ __forceinline__ void stage16(const float* __restrict__ src,
                                        ushort* __restrict__ dh,
                                        ushort* __restrict__ dl)
{
    ushort h[16], l[16];
    #pragma unroll
    for (int i = 0; i < 16; i += 4) {
        float4 v = *(const float4*)(src + i);
        cvt2(v.x, h[i],   l[i]);
        cvt2(v.y, h[i+1], l[i+1]);
        cvt2(v.z, h[i+2], l[i+2]);
        cvt2(v.w, h[i+3], l[i+3]);
    }
    *(uint4*)(dh)     = uint4{pk(h[0],h[1]),pk(h[2],h[3]),pk(h[4],h[5]),pk(h[6],h[7])};
    *(uint4*)(dh + 8) = uint4{pk(h[8],h[9]),pk(h[10],h[11]),pk(h[12],h[13]),pk(h[14],h[15])};
    *(uint4*)(dl)     = uint4{pk(l[0],l[1]),pk(l[2],l[3]),pk(l[4],l[5]),pk(l[6],l[7])};
    *(uint4*)(dl + 8) = uint4{pk(l[8],l[9]),pk(l[10],l[11]),pk(l[12],l[13]),pk(l[14],l[15])};
}

// ===========================================================================
// gemm64: one 64(M) x 256(N) x 1024(K) tile, 512 thr = 8 waves (1x8),
// 4x2 16x16 frags/wave, 3xBF16 split.
// mode 0: A = emb gather(ids), C -> Cmb (tagged)     [pre_enc]
// mode 1: gather shifted                              [pre_dec]
// mode 2: A = Amb (tagged mailbox), C -> plain        [logits]
//   SENTINEL GATE: wait (1 lane, 1 element, long sleep) on the quarter's
//   LAST row; rows publish in t-order so the quarter is then present.
//   Per-element tagged reads remain as a rarely-taken backstop.
// ===========================================================================
__device__ void gemm64(int mode, int m0, int n0,
    const float* __restrict__ A, const int* __restrict__ ids,
    const u64* __restrict__ Amb,
    const float* __restrict__ B, const float* __restrict__ b1,
    const float* __restrict__ b2,
    float* __restrict__ C, u64* __restrict__ Cmb, int ldc,
    ushort* Ah, ushort* Al, ushort* Bh, ushort* Bl, int* idsb, int tid)
{
    if (mode != 2 && tid < 64) {
        int m = m0 + tid;
        idsb[tid] = (mode == 1) ? ((m == 0) ? 0 : ids[m - 1]) : ids[m];
    }
    if (mode == 2 && tid == 0) {
        // sentinel: one element of the quarter's last row; spread lines
        const u64* sp = Amb + (size_t)(m0 + 63) * HD
                            + (unsigned)((m0 * 7 + (n0 >> 2)) & 1023);
        while ((unsigned)(al64(sp) >> 32) == 0u)
            __builtin_amdgcn_s_sleep(32);
    }
    __syncthreads();

    const int lane = tid & 63, wid = tid >> 6;
    const int wn  = wid * 32;
    const int sr  = tid >> 3, sc  = (tid & 7) * 4;   // A: 64 rows x 4 floats
    const int sr2 = tid >> 1, sc2 = (tid & 1) * 16;  // B: 256 rows x 16 floats
    const int fr = lane & 15, kg = (lane >> 4) * 8, rg = (lane >> 4) * 4;

    const float* brow = B + (size_t)(n0 + sr2) * HD;

    f32x4 acc[4][2] = {};

    for (int k0 = 0; k0 < HD; k0 += 32) {
        __syncthreads();
        {
            float av[4];
            if (mode == 2) {
                const u64* ap = Amb + (size_t)(m0 + sr) * HD + k0 + sc;
                #pragma unroll
                for (int i = 0; i < 4; ++i) {
                    u64 e = al64(ap + i);
                    while ((unsigned)(e >> 32) == 0u) {   // backstop (rare)
                        __builtin_amdgcn_s_sleep(2);
                        e = al64(ap + i);
                    }
                    av[i] = lo_f(e);
                }
            } else {
                float4 v = *(const float4*)(A + (size_t)idsb[sr] * HD + k0 + sc);
                av[0] = v.x; av[1] = v.y; av[2] = v.z; av[3] = v.w;
            }
            ushort h4[4], l4[4];
            #pragma unroll
            for (int i = 0; i < 4; ++i) cvt2(av[i], h4[i], l4[i]);
            *(uint2*)&Ah[sr * LDT + sc] = uint2{pk(h4[0],h4[1]), pk(h4[2],h4[3])};
            *(uint2*)&Al[sr * LDT + sc] = uint2{pk(l4[0],l4[1]), pk(l4[2],l4[3])};
        }
        stage16(brow + k0 + sc2, &Bh[sr2 * LDT + sc2], &Bl[sr2 * LDT + sc2]);
        __syncthreads();

        short8 fah[4], fal[4], fbh[2], fbl[2];
        #pragma unroll
        for (int f = 0; f < 4; ++f) {
            fah[f] = *(const short8*)&Ah[(f * 16 + fr) * LDT + kg];
            fal[f] = *(const short8*)&Al[(f * 16 + fr) * LDT + kg];
        }
        #pragma unroll
        for (int f = 0; f < 2; ++f) {
            fbh[f] = *(const short8*)&Bh[(wn + f * 16 + fr) * LDT + kg];
            fbl[f] = *(const short8*)&Bl[(wn + f * 16 + fr) * LDT + kg];
        }
        #pragma unroll
        for (int fi = 0; fi < 4; ++fi)
            #pragma unroll
            for (int fj = 0; fj < 2; ++fj) {
                acc[fi][fj] = __builtin_amdgcn_mfma_f32_16x16x32_bf16(
                                  fah[fi], fbh[fj], acc[fi][fj], 0, 0, 0);
                acc[fi][fj] = __builtin_amdgcn_mfma_f32_16x16x32_bf16(
                                  fah[fi], fbl[fj], acc[fi][fj], 0, 0, 0);
                acc[fi][fj] = __builtin_amdgcn_mfma_f32_16x16x32_bf16(
                                  fal[fi], fbh[fj], acc[fi][fj], 0, 0, 0);
            }
    }

    #pragma unroll
    for (int fj = 0; fj < 2; ++fj) {
        int col = n0 + wn + fj * 16 + fr;
        float bs = b1[col];
        if (b2) bs += b2[col];
        #pragma unroll
        for (int fi = 0; fi < 4; ++fi) {
            #pragma unroll
            for (int r = 0; r < 4; ++r) {
                int rowi = m0 + fi * 16 + rg + r;
                float val = acc[fi][fj][r] + bs;
                if (mode == 2) C[(size_t)rowi * ldc + col] = val;
                else           as64(&Cmb[(size_t)rowi * ldc + col], packhv(val, 1u));
            }
        }
    }
}

// ===========================================================================
// seq pieces (identical to rounds 8-9 passing version)
// ===========================================================================
__device__ __forceinline__ void load_w(float4 (&wreg)[32],
                                       const float* __restrict__ w,
                                       int row, int s)
{
    const float4* p = (const float4*)(w + (size_t)row * HD + s * 128);
    #pragma unroll
    for (int u = 0; u < 32; ++u) wreg[u] = p[u];
}

__device__ __forceinline__ void read_h(const u64* mb, unsigned v,
                                       float* h_lds, int tid)
{
    const u64* p = mb + (size_t)(v & 1u) * HD + tid * 2;
    u64 e0, e1;
    for (;;) {
        e0 = al64(p); e1 = al64(p + 1);
        if ((unsigned)(e0 >> 32) >= v && (unsigned)(e1 >> 32) >= v) break;
        __builtin_amdgcn_s_sleep(1);
    }
    int j = tid * 2;
    *(float2*)&h_lds[(j >> 7) * WCH + (j & 127)] =
        make_float2(lo_f(e0), lo_f(e1));
}

// thread layout: tid = jl*32 + gate*8 + s  (jl 0..15, gate 0..3, s 0..7)
__device__ __forceinline__ void lstm_loop(
    const u64* __restrict__ pre, u64* mb, u64* hs_mb,
    float& c_reg, const float4 (&wreg)[32], float* h_lds,
    int tid, int s, int gate, int row, int jown, int own, unsigned vbase)
{
    const int lane = tid & 63;
    u64 pe = 0;
    if (s == 0) pe = al64(pre + row);          // t=0 prefetch
    for (int t = 0; t < TT; ++t) {
        unsigned v = vbase + (unsigned)t;
        __syncthreads();                       // protect h_lds readers of t-1

        float pv = 0.f;
        if (s == 0) {
            const u64* pp = pre + (size_t)t * G4 + row;
            while ((unsigned)(pe >> 32) == 0u) {
                __builtin_amdgcn_s_sleep(1);
                pe = al64(pp);
            }
            pv = lo_f(pe);
            if (t + 1 < TT) pe = al64(pp + G4);  // prefetch next step
        }

        read_h(mb, v, h_lds, tid);
        __syncthreads();

        const float4* h4 = (const float4*)h_lds;
        float a0 = 0.f, a1 = 0.f, a2 = 0.f, a3 = 0.f;
        #pragma unroll
        for (int u = 0; u < 32; ++u) {
            float4 wv = wreg[u];
            float4 hv = h4[s * 33 + u];
            a0 = fmaf(wv.x, hv.x, a0);
            a1 = fmaf(wv.y, hv.y, a1);
            a2 = fmaf(wv.z, hv.z, a2);
            a3 = fmaf(wv.w, hv.w, a3);
        }
        float acc = (a0 + a1) + (a2 + a3);
        acc += __shfl_xor(acc, 1);
        acc += __shfl_xor(acc, 2);
        acc += __shfl_xor(acc, 4);

        float x = acc + pv;                             // valid at s==0 lanes
        float a = (gate == 2) ? tanh_f(x) : sig_f(x);   // valid at gate lanes
        float xf = __shfl(a, lane + 8);
        float xg = __shfl(a, lane + 16);
        float xo = __shfl(a, lane + 24);
        if (own) {
            c_reg = xf * c_reg + a * xg;
            float hv2 = xo * tanh_f(c_reg);
            as64(&mb[(size_t)((v + 1u) & 1u) * HD + jown], packhv(hv2, v + 1u));
            if (hs_mb) as64(&hs_mb[(size_t)t * HD + jown], packhv(hv2, 1u));
        }
    }
}

__device__ void seq_role(
    const float* cond_emb, const float* enc_whh,
    const float* mean_w, const float* mean_b,
    const float* lgv_w, const float* lgv_b,
    const float* l2h_w, const float* l2h_b,
    const float* l2c_w, const float* l2c_b,
    const float* dec_whh, const float* eps,
    const int* p_ic, const int* p_tc,
    const u64* pre_enc, const u64* pre_dec,
    u64* mb, u64* zmb, u64* hs_mb, float* out_mlgv,
    float* h_lds, float* red_s, float* sm_s, int w, int tid)
{
    const int s    = tid & 7;
    const int rl   = tid >> 3;        // 0..63
    const int gate = rl & 3;
    const int jl   = rl >> 2;         // 0..15
    const int row  = gate * HD + w * 16 + jl;
    const int own  = ((tid & 31) == 0);
    const int jown = w * 16 + (tid >> 5);   // valid at owners
    float c_reg = 0.f;

    if (tid < 16) {
        int j = w * 16 + tid;
        float v0 = 0.f;
        int ic = p_ic[0];
        if (j >= HD - CND) v0 = cond_emb[ic * CND + (j - (HD - CND))];
        as64(&mb[(size_t)1 * HD + j], packhv(v0, 1u));
    }

    float4 wreg[32];
    load_w(wreg, enc_whh, row, s);
    lstm_loop(pre_enc, mb, nullptr, c_reg, wreg, h_lds,
              tid, s, gate, row, jown, own, 1u);

    // ---- latent 1: read hT (version 257), compute m, lgv, z ----
    __syncthreads();
    read_h(mb, TT + 1u, h_lds, tid);
    __syncthreads();
    {
        int d = tid >> 6;             // 0..7; <4: mean, >=4: lgv
        int l64 = tid & 63;
        int l = w * 4 + (d & 3);
        const float* wrow = (d < 4 ? mean_w : lgv_w) + (size_t)l * HD;
        float acc = 0.f;
        #pragma unroll
        for (int e = 0; e < 16; ++e) {
            int k = e * 64 + l64;
            acc = fmaf(wrow[k], h_lds[(k >> 7) * WCH + (k & 127)], acc);
        }
        #pragma unroll
        for (int o = 32; o >= 1; o >>= 1) acc += __shfl_xor(acc, o);
        if (l64 == 0) sm_s[d] = acc + (d < 4 ? mean_b : lgv_b)[l];
    }
    __syncthreads();
    if (tid < 4) {
        int l = w * 4 + tid;
        float m = sm_s[tid], lg = sm_s[4 + tid];
        float z = eps[l] * __expf(0.5f * lg) + m;
        as64(&zmb[l], packhv(z, 1u));
        out_mlgv[l]       = m;
        out_mlgv[LAT + l] = lg;
    }

    // ---- latent 2: poll z, build zc in LDS, compute dh0/dc0 ----
    if (tid < LAT) {
        u64 e;
        const u64* p = zmb + tid;
        do { e = al64(p); } while ((unsigned)(e >> 32) < 1u);
        h_lds[tid] = lo_f(e);
    } else if (tid < ZCN) {
        int tc = p_tc[0];
        h_lds[tid] = cond_emb[tc * CND + (tid - LAT)];
    }
    __syncthreads();
    {
        int r2 = tid >> 4;            // 0..31 (16 dh rows + 16 dc rows)
        int l16 = tid & 15;
        int which = r2 >> 4;
        int i = w * 16 + (r2 & 15);
        const float* wrow = (which ? l2c_w : l2h_w) + (size_t)i * ZCN;
        float acc = 0.f;
        #pragma unroll
        for (int e = 0; e < 20; ++e) {
            int k = e * 16 + l16;
            acc = fmaf(wrow[k], h_lds[k], acc);
        }
        acc += __shfl_xor(acc, 1);
        acc += __shfl_xor(acc, 2);
        acc += __shfl_xor(acc, 4);
        acc += __shfl_xor(acc, 8);
        if (l16 == 0) red_s[r2] = acc + (which ? l2c_b : l2h_b)[i];
    }
    __syncthreads();
    if (tid < 16)
        as64(&mb[(size_t)1 * HD + w * 16 + tid], packhv(red_s[tid], DEC0));
    if (own) c_reg = red_s[16 + (tid >> 5)];   // dc0

    load_w(wreg, dec_whh, row, s);
    lstm_loop(pre_dec, mb, hs_mb, c_reg, wreg, h_lds,
              tid, s, gate, row, jown, own, DEC0);
}

// ===========================================================================
// worker role: static tile assignment, zero RMW atomics, zero counters.
// pre:  k < 128 -> one 64x256 pre tile.
// out:  n-MAJOR chunks: worker k owns tiles j in [k*500/NWKR,(k+1)*500/NWKR),
//       j = n*4 + q (q fastest). Same out_w panel reused q=0..3 back-to-back
//       -> out_w read from HBM once, later quarters hit IC (128 MB < 256 MB).
//       q ascending matches sentinel-open order.
// ===========================================================================
__device__ void worker_role(int k,
    const float* enc_emb, const int* input_ids,
    const float* enc_wih, const float* enc_bih, const float* enc_bhh,
    const float* dec_emb, const int* target_ids,
    const float* dec_wih, const float* dec_bih, const float* dec_bhh,
    const float* out_w, const float* out_b,
    u64* pre_enc, u64* pre_dec, const u64* hs_mb, float* outp,
    ushort* Ah, ushort* Al, ushort* Bh, ushort* Bl, int* idsb, int tid)
{
    if (k < 128) {
        int dir = k >> 6, idx = k & 63;
        int m0 = (idx >> 4) * 64, n0 = (idx & 15) * 256;
        if (dir == 0)
            gemm64(0, m0, n0, enc_emb, input_ids, nullptr, enc_wih,
                   enc_bih, enc_bhh, nullptr, pre_enc, G4,
                   Ah, Al, Bh, Bl, idsb, tid);
        else
            gemm64(1, m0, n0, dec_emb, target_ids, nullptr, dec_wih,
                   dec_bih, dec_bhh, nullptr, pre_dec, G4,
                   Ah, Al, Bh, Bl, idsb, tid);
    }
    const int j0 = (k * 500) / NWKR;
    const int j1 = ((k + 1) * 500) / NWKR;
    for (int j = j0; j < j1; ++j) {
        int n0 = (j >> 2) * 256, m0 = (j & 3) * 64;
        gemm64(2, m0, n0, nullptr, nullptr, hs_mb, out_w, out_b, nullptr,
               outp, nullptr, VOC, Ah, Al, Bh, Bl, idsb, tid);
    }
}

// ===========================================================================
__global__ __launch_bounds__(THR, 2) void k_fused(
    const float* cond_emb, const float* enc_emb,
    const float* enc_wih, const float* enc_whh,
    const float* enc_bih, const float* enc_bhh,
    const float* mean_w, const float* mean_b,
    const float* lgv_w, const float* lgv_b,
    const float* l2h_w, const float* l2h_b,
    const float* l2c_w, const float* l2c_b,
    const float* dec_emb, const float* dec_wih, const float* dec_whh,
    const float* dec_bih, const float* dec_bhh,
    const float* out_w, const float* out_b, const float* eps,
    const int* input_ids, const int* target_ids,
    const int* p_ic, const int* p_tc,
    u64* pre_mb, u64* hs_mb, u64* mb, u64* zmb,
    float* outp, float* out_mlgv)
{
    __shared__ float  h_lds[8 * WCH];
    __shared__ float  red_s[32];
    __shared__ float  sm_s[8];
    __shared__ ushort AhS[64 * LDT];
    __shared__ ushort AlS[64 * LDT];
    __shared__ ushort BhS[256 * LDT];
    __shared__ ushort BlS[256 * LDT];
    __shared__ int    idsb_s[64];

    const int wg  = blockIdx.x;
    const int tid = threadIdx.x;
    u64* pre_enc = pre_mb;
    u64* pre_dec = pre_mb + (size_t)TT * G4;

    if (wg < NSEQ) {
        seq_role(cond_emb, enc_whh, mean_w, mean_b, lgv_w, lgv_b,
                 l2h_w, l2h_b, l2c_w, l2c_b, dec_whh, eps, p_ic, p_tc,
                 pre_enc, pre_dec, mb, zmb, hs_mb, out_mlgv,
                 h_lds, red_s, sm_s, wg, tid);
    } else {
        worker_role(wg - NSEQ, enc_emb, input_ids, enc_wih, enc_bih, enc_bhh,
                    dec_emb, target_ids, dec_wih, dec_bih, dec_bhh,
                    out_w, out_b, pre_enc, pre_dec, hs_mb, outp,
                    AhS, AlS, BhS, BlS, idsb_s, tid);
    }
}

// ---------------------------------------------------------------------------
extern "C" void kernel_launch(void* const* d_in, const int* in_sizes, int n_in,
                              void* d_out, int out_size, void* d_ws, size_t ws_size,
                              hipStream_t stream)
{
    const float* cond_emb = (const float*)d_in[0];
    const float* enc_emb  = (const float*)d_in[1];
    const float* enc_wih  = (const float*)d_in[2];
    const float* enc_whh  = (const float*)d_in[3];
    const float* enc_bih  = (const float*)d_in[4];
    const float* enc_bhh  = (const float*)d_in[5];
    const float* mean_w   = (const float*)d_in[6];
    const float* mean_b   = (const float*)d_in[7];
    const float* lgv_w    = (const float*)d_in[8];
    const float* lgv_b    = (const float*)d_in[9];
    const float* l2h_w    = (const float*)d_in[10];
    const float* l2h_b    = (const float*)d_in[11];
    const float* l2c_w    = (const float*)d_in[12];
    const float* l2c_b    = (const float*)d_in[13];
    const float* dec_emb  = (const float*)d_in[14];
    const float* dec_wih  = (const float*)d_in[15];
    const float* dec_whh  = (const float*)d_in[16];
    const float* dec_bih  = (const float*)d_in[17];
    const float* dec_bhh  = (const float*)d_in[18];
    const float* out_w    = (const float*)d_in[19];
    const float* out_b    = (const float*)d_in[20];
    const float* eps      = (const float*)d_in[21];
    const int* input_ids  = (const int*)d_in[22];
    const int* target_ids = (const int*)d_in[23];
    const int* p_ic       = (const int*)d_in[24];
    const int* p_tc       = (const int*)d_in[25];

    u64* pre_mb = (u64*)d_ws;                       // 2*TT*G4 entries (16 MB)
    u64* hs_mb  = pre_mb + (size_t)2 * TT * G4;     // TT*HD (2 MB)
    u64* mb     = hs_mb + (size_t)TT * HD;          // 2*HD
    u64* zmb    = mb + 2 * HD;                      // LAT

    float* outp     = (float*)d_out;
    float* out_mlgv = outp + (size_t)TT * VOC;

    size_t mb_total = ((size_t)2 * TT * G4 + (size_t)TT * HD + 2 * HD + LAT)
                      * sizeof(u64);
    hipMemsetAsync(pre_mb, 0, mb_total, stream);

    void* args[] = {
        (void*)&cond_emb, (void*)&enc_emb, (void*)&enc_wih, (void*)&enc_whh,
        (void*)&enc_bih, (void*)&enc_bhh, (void*)&mean_w, (void*)&mean_b,
        (void*)&lgv_w, (void*)&lgv_b, (void*)&l2h_w, (void*)&l2h_b,
        (void*)&l2c_w, (void*)&l2c_b, (void*)&dec_emb, (void*)&dec_wih,
        (void*)&dec_whh, (void*)&dec_bih, (void*)&dec_bhh, (void*)&out_w,
        (void*)&out_b, (void*)&eps, (void*)&input_ids, (void*)&target_ids,
        (void*)&p_ic, (void*)&p_tc, (void*)&pre_mb, (void*)&hs_mb,
        (void*)&mb, (void*)&zmb, (void*)&outp, (void*)&out_mlgv
    };
    hipLaunchCooperativeKernel((const void*)k_fused, dim3(NSEQ + NWKR),
                               dim3(THR), args, 0, stream);
}

// Round 11
// 1171.921 us; speedup vs baseline: 1.1557x; 1.1557x over previous
//
#include <hip/hip_runtime.h>
#include <hip/hip_bf16.h>

#define HD   1024
#define G4   4096
#define CND  64
#define LAT  256
#define VOC  32000
#define TT   256
#define ZCN  320    // LAT + CND
#define NSEQ 64     // seq WGs
#define NWKR 160    // worker WGs
#define THR  512
#define DEC0 301u   // decoder h version base (encoder uses 1..257)
#define WCH  132    // LDS chunk stride (floats)
#define LDT  40     // gemm LDS tile row stride (ushorts)

typedef unsigned long long u64;
typedef __attribute__((ext_vector_type(8))) short short8;
typedef __attribute__((ext_vector_type(4))) float f32x4;

__device__ __forceinline__ float sig_f(float x) {
    return 1.0f / (1.0f + __expf(-x));
}
__device__ __forceinline__ float tanh_f(float x) {
    float e = __expf(2.0f * x);
    return 1.0f - 2.0f / (e + 1.0f);
}
__device__ __forceinline__ u64 al64(const u64* p) {
    return __hip_atomic_load((u64*)p, __ATOMIC_RELAXED, __HIP_MEMORY_SCOPE_AGENT);
}
__device__ __forceinline__ void as64(u64* p, u64 v) {
    __hip_atomic_store(p, v, __ATOMIC_RELAXED, __HIP_MEMORY_SCOPE_AGENT);
}
__device__ __forceinline__ u64 packhv(float h, unsigned tag) {
    return ((u64)tag << 32) | (u64)__float_as_uint(h);
}
__device__ __forceinline__ float lo_f(u64 e) {
    return __uint_as_float((unsigned)e);
}

// ===========================================================================
// 3xBF16-split helpers (proven rounds 5-9)
// ===========================================================================
__device__ __forceinline__ void cvt2(float x, ushort& h, ushort& l)
{
    unsigned u = __float_as_uint(x);
    h = (ushort)(u >> 16);
    float hif = __uint_as_float(u & 0xffff0000u);
    l = (ushort)(__float_as_uint(x - hif) >> 16);
}
__device__ __forceinline__ unsigned pk(ushort a, ushort b)
{
    return (unsigned)a | ((unsigned)b << 16);
}
__device__ __forceinline__ void stage16(const float* __restrict__ src,
                                        ushort* __restrict__ dh,
                                        ushort* __restrict__ dl)
{
    ushort h[16], l[16];
    #pragma unroll
    for (int i = 0; i < 16; i += 4) {
        float4 v = *(const float4*)(src + i);
        cvt2(v.x, h[i],   l[i]);
        cvt2(v.y, h[i+1], l[i+1]);
        cvt2(v.z, h[i+2], l[i+2]);
        cvt2(v.w, h[i+3], l[i+3]);
    }
    *(uint4*)(dh)     = uint4{pk(h[0],h[1]),pk(h[2],h[3]),pk(h[4],h[5]),pk(h[6],h[7])};
    *(uint4*)(dh + 8) = uint4{pk(h[8],h[9]),pk(h[10],h[11]),pk(h[12],h[13]),pk(h[14],h[15])};
    *(uint4*)(dl)     = uint4{pk(l[0],l[1]),pk(l[2],l[3]),pk(l[4],l[5]),pk(l[6],l[7])};
    *(uint4*)(dl + 8) = uint4{pk(l[8],l[9]),pk(l[10],l[11]),pk(l[12],l[13]),pk(l[14],l[15])};
}

// ===========================================================================
// gemm64: one 64(M) x 256(N) x 1024(K) tile, 512 thr = 8 waves (1x8),
// 4x2 16x16 frags/wave, 3xBF16 split.
// mode 0: A = emb gather(ids), C -> Cmb (tagged)     [pre_enc]
// mode 1: gather shifted                              [pre_dec]
// mode 2: A = Amb (tagged mailbox), C -> plain        [logits]
//   SENTINEL GATE: wait (1 lane, 1 element, long sleep) on the quarter's
//   LAST row; rows publish in t-order so the quarter is then present.
//   Per-element tagged reads remain as a rarely-taken backstop.
// ===========================================================================
__device__ void gemm64(int mode, int m0, int n0,
    const float* __restrict__ A, const int* __restrict__ ids,
    const u64* __restrict__ Amb,
    const float* __restrict__ B, const float* __restrict__ b1,
    const float* __restrict__ b2,
    float* __restrict__ C, u64* __restrict__ Cmb, int ldc,
    ushort* Ah, ushort* Al, ushort* Bh, ushort* Bl, int* idsb, int tid)
{
    if (mode != 2 && tid < 64) {
        int m = m0 + tid;
        idsb[tid] = (mode == 1) ? ((m == 0) ? 0 : ids[m - 1]) : ids[m];
    }
    if (mode == 2 && tid == 0) {
        // sentinel: one element of the quarter's last row; spread lines
        const u64* sp = Amb + (size_t)(m0 + 63) * HD
                            + (unsigned)((m0 * 7 + (n0 >> 2)) & 1023);
        while ((unsigned)(al64(sp) >> 32) == 0u)
            __builtin_amdgcn_s_sleep(96);
    }
    __syncthreads();

    const int lane = tid & 63, wid = tid >> 6;
    const int wn  = wid * 32;
    const int sr  = tid >> 3, sc  = (tid & 7) * 4;   // A: 64 rows x 4 floats
    const int sr2 = tid >> 1, sc2 = (tid & 1) * 16;  // B: 256 rows x 16 floats
    const int fr = lane & 15, kg = (lane >> 4) * 8, rg = (lane >> 4) * 4;

    const float* brow = B + (size_t)(n0 + sr2) * HD;

    f32x4 acc[4][2] = {};

    for (int k0 = 0; k0 < HD; k0 += 32) {
        __syncthreads();
        {
            float av[4];
            if (mode == 2) {
                const u64* ap = Amb + (size_t)(m0 + sr) * HD + k0 + sc;
                #pragma unroll
                for (int i = 0; i < 4; ++i) {
                    u64 e = al64(ap + i);
                    while ((unsigned)(e >> 32) == 0u) {   // backstop (rare)
                        __builtin_amdgcn_s_sleep(2);
                        e = al64(ap + i);
                    }
                    av[i] = lo_f(e);
                }
            } else {
                float4 v = *(const float4*)(A + (size_t)idsb[sr] * HD + k0 + sc);
                av[0] = v.x; av[1] = v.y; av[2] = v.z; av[3] = v.w;
            }
            ushort h4[4], l4[4];
            #pragma unroll
            for (int i = 0; i < 4; ++i) cvt2(av[i], h4[i], l4[i]);
            *(uint2*)&Ah[sr * LDT + sc] = uint2{pk(h4[0],h4[1]), pk(h4[2],h4[3])};
            *(uint2*)&Al[sr * LDT + sc] = uint2{pk(l4[0],l4[1]), pk(l4[2],l4[3])};
        }
        stage16(brow + k0 + sc2, &Bh[sr2 * LDT + sc2], &Bl[sr2 * LDT + sc2]);
        __syncthreads();

        short8 fah[4], fal[4], fbh[2], fbl[2];
        #pragma unroll
        for (int f = 0; f < 4; ++f) {
            fah[f] = *(const short8*)&Ah[(f * 16 + fr) * LDT + kg];
            fal[f] = *(const short8*)&Al[(f * 16 + fr) * LDT + kg];
        }
        #pragma unroll
        for (int f = 0; f < 2; ++f) {
            fbh[f] = *(const short8*)&Bh[(wn + f * 16 + fr) * LDT + kg];
            fbl[f] = *(const short8*)&Bl[(wn + f * 16 + fr) * LDT + kg];
        }
        #pragma unroll
        for (int fi = 0; fi < 4; ++fi)
            #pragma unroll
            for (int fj = 0; fj < 2; ++fj) {
                acc[fi][fj] = __builtin_amdgcn_mfma_f32_16x16x32_bf16(
                                  fah[fi], fbh[fj], acc[fi][fj], 0, 0, 0);
                acc[fi][fj] = __builtin_amdgcn_mfma_f32_16x16x32_bf16(
                                  fah[fi], fbl[fj], acc[fi][fj], 0, 0, 0);
                acc[fi][fj] = __builtin_amdgcn_mfma_f32_16x16x32_bf16(
                                  fal[fi], fbh[fj], acc[fi][fj], 0, 0, 0);
            }
    }

    #pragma unroll
    for (int fj = 0; fj < 2; ++fj) {
        int col = n0 + wn + fj * 16 + fr;
        float bs = b1[col];
        if (b2) bs += b2[col];
        #pragma unroll
        for (int fi = 0; fi < 4; ++fi) {
            #pragma unroll
            for (int r = 0; r < 4; ++r) {
                int rowi = m0 + fi * 16 + rg + r;
                float val = acc[fi][fj][r] + bs;
                if (mode == 2) C[(size_t)rowi * ldc + col] = val;
                else           as64(&Cmb[(size_t)rowi * ldc + col], packhv(val, 1u));
            }
        }
    }
}

// ===========================================================================
// seq pieces (identical to rounds 8-9 passing version)
// ===========================================================================
__device__ __forceinline__ void load_w(float4 (&wreg)[32],
                                       const float* __restrict__ w,
                                       int row, int s)
{
    const float4* p = (const float4*)(w + (size_t)row * HD + s * 128);
    #pragma unroll
    for (int u = 0; u < 32; ++u) wreg[u] = p[u];
}

__device__ __forceinline__ void read_h(const u64* mb, unsigned v,
                                       float* h_lds, int tid)
{
    const u64* p = mb + (size_t)(v & 1u) * HD + tid * 2;
    u64 e0, e1;
    for (;;) {
        e0 = al64(p); e1 = al64(p + 1);
        if ((unsigned)(e0 >> 32) >= v && (unsigned)(e1 >> 32) >= v) break;
        __builtin_amdgcn_s_sleep(1);
    }
    int j = tid * 2;
    *(float2*)&h_lds[(j >> 7) * WCH + (j & 127)] =
        make_float2(lo_f(e0), lo_f(e1));
}

// thread layout: tid = jl*32 + gate*8 + s  (jl 0..15, gate 0..3, s 0..7)
__device__ __forceinline__ void lstm_loop(
    const u64* __restrict__ pre, u64* mb, u64* hs_mb,
    float& c_reg, const float4 (&wreg)[32], float* h_lds,
    int tid, int s, int gate, int row, int jown, int own, unsigned vbase)
{
    const int lane = tid & 63;
    u64 pe = 0;
    if (s == 0) pe = al64(pre + row);          // t=0 prefetch
    for (int t = 0; t < TT; ++t) {
        unsigned v = vbase + (unsigned)t;
        __syncthreads();                       // protect h_lds readers of t-1

        float pv = 0.f;
        if (s == 0) {
            const u64* pp = pre + (size_t)t * G4 + row;
            while ((unsigned)(pe >> 32) == 0u) {
                __builtin_amdgcn_s_sleep(1);
                pe = al64(pp);
            }
            pv = lo_f(pe);
            if (t + 1 < TT) pe = al64(pp + G4);  // prefetch next step
        }

        read_h(mb, v, h_lds, tid);
        __syncthreads();

        const float4* h4 = (const float4*)h_lds;
        float a0 = 0.f, a1 = 0.f, a2 = 0.f, a3 = 0.f;
        #pragma unroll
        for (int u = 0; u < 32; ++u) {
            float4 wv = wreg[u];
            float4 hv = h4[s * 33 + u];
            a0 = fmaf(wv.x, hv.x, a0);
            a1 = fmaf(wv.y, hv.y, a1);
            a2 = fmaf(wv.z, hv.z, a2);
            a3 = fmaf(wv.w, hv.w, a3);
        }
        float acc = (a0 + a1) + (a2 + a3);
        acc += __shfl_xor(acc, 1);
        acc += __shfl_xor(acc, 2);
        acc += __shfl_xor(acc, 4);

        float x = acc + pv;                             // valid at s==0 lanes
        float a = (gate == 2) ? tanh_f(x) : sig_f(x);   // valid at gate lanes
        float xf = __shfl(a, lane + 8);
        float xg = __shfl(a, lane + 16);
        float xo = __shfl(a, lane + 24);
        if (own) {
            c_reg = xf * c_reg + a * xg;
            float hv2 = xo * tanh_f(c_reg);
            as64(&mb[(size_t)((v + 1u) & 1u) * HD + jown], packhv(hv2, v + 1u));
            if (hs_mb) as64(&hs_mb[(size_t)t * HD + jown], packhv(hv2, 1u));
        }
    }
}

__device__ void seq_role(
    const float* cond_emb, const float* enc_whh,
    const float* mean_w, const float* mean_b,
    const float* lgv_w, const float* lgv_b,
    const float* l2h_w, const float* l2h_b,
    const float* l2c_w, const float* l2c_b,
    const float* dec_whh, const float* eps,
    const int* p_ic, const int* p_tc,
    const u64* pre_enc, const u64* pre_dec,
    u64* mb, u64* zmb, u64* hs_mb, float* out_mlgv,
    float* h_lds, float* red_s, float* sm_s, int w, int tid)
{
    const int s    = tid & 7;
    const int rl   = tid >> 3;        // 0..63
    const int gate = rl & 3;
    const int jl   = rl >> 2;         // 0..15
    const int row  = gate * HD + w * 16 + jl;
    const int own  = ((tid & 31) == 0);
    const int jown = w * 16 + (tid >> 5);   // valid at owners
    float c_reg = 0.f;

    if (tid < 16) {
        int j = w * 16 + tid;
        float v0 = 0.f;
        int ic = p_ic[0];
        if (j >= HD - CND) v0 = cond_emb[ic * CND + (j - (HD - CND))];
        as64(&mb[(size_t)1 * HD + j], packhv(v0, 1u));
    }

    float4 wreg[32];
    load_w(wreg, enc_whh, row, s);
    lstm_loop(pre_enc, mb, nullptr, c_reg, wreg, h_lds,
              tid, s, gate, row, jown, own, 1u);

    // ---- latent 1: read hT (version 257), compute m, lgv, z ----
    __syncthreads();
    read_h(mb, TT + 1u, h_lds, tid);
    __syncthreads();
    {
        int d = tid >> 6;             // 0..7; <4: mean, >=4: lgv
        int l64 = tid & 63;
        int l = w * 4 + (d & 3);
        const float* wrow = (d < 4 ? mean_w : lgv_w) + (size_t)l * HD;
        float acc = 0.f;
        #pragma unroll
        for (int e = 0; e < 16; ++e) {
            int k = e * 64 + l64;
            acc = fmaf(wrow[k], h_lds[(k >> 7) * WCH + (k & 127)], acc);
        }
        #pragma unroll
        for (int o = 32; o >= 1; o >>= 1) acc += __shfl_xor(acc, o);
        if (l64 == 0) sm_s[d] = acc + (d < 4 ? mean_b : lgv_b)[l];
    }
    __syncthreads();
    if (tid < 4) {
        int l = w * 4 + tid;
        float m = sm_s[tid], lg = sm_s[4 + tid];
        float z = eps[l] * __expf(0.5f * lg) + m;
        as64(&zmb[l], packhv(z, 1u));
        out_mlgv[l]       = m;
        out_mlgv[LAT + l] = lg;
    }

    // ---- latent 2: poll z, build zc in LDS, compute dh0/dc0 ----
    if (tid < LAT) {
        u64 e;
        const u64* p = zmb + tid;
        do { e = al64(p); } while ((unsigned)(e >> 32) < 1u);
        h_lds[tid] = lo_f(e);
    } else if (tid < ZCN) {
        int tc = p_tc[0];
        h_lds[tid] = cond_emb[tc * CND + (tid - LAT)];
    }
    __syncthreads();
    {
        int r2 = tid >> 4;            // 0..31 (16 dh rows + 16 dc rows)
        int l16 = tid & 15;
        int which = r2 >> 4;
        int i = w * 16 + (r2 & 15);
        const float* wrow = (which ? l2c_w : l2h_w) + (size_t)i * ZCN;
        float acc = 0.f;
        #pragma unroll
        for (int e = 0; e < 20; ++e) {
            int k = e * 16 + l16;
            acc = fmaf(wrow[k], h_lds[k], acc);
        }
        acc += __shfl_xor(acc, 1);
        acc += __shfl_xor(acc, 2);
        acc += __shfl_xor(acc, 4);
        acc += __shfl_xor(acc, 8);
        if (l16 == 0) red_s[r2] = acc + (which ? l2c_b : l2h_b)[i];
    }
    __syncthreads();
    if (tid < 16)
        as64(&mb[(size_t)1 * HD + w * 16 + tid], packhv(red_s[tid], DEC0));
    if (own) c_reg = red_s[16 + (tid >> 5)];   // dc0

    load_w(wreg, dec_whh, row, s);
    lstm_loop(pre_dec, mb, hs_mb, c_reg, wreg, h_lds,
              tid, s, gate, row, jown, own, DEC0);
}

// ===========================================================================
// worker role: static tile assignment, zero RMW atomics, zero counters.
// quarter-major stride (round-9 proven): worker k does j = k, k+160, ... ;
// one tile per quarter, naturally pipelined with decoder gate-openings.
// ===========================================================================
__device__ void worker_role(int k,
    const float* enc_emb, const int* input_ids,
    const float* enc_wih, const float* enc_bih, const float* enc_bhh,
    const float* dec_emb, const int* target_ids,
    const float* dec_wih, const float* dec_bih, const float* dec_bhh,
    const float* out_w, const float* out_b,
    u64* pre_enc, u64* pre_dec, const u64* hs_mb, float* outp,
    ushort* Ah, ushort* Al, ushort* Bh, ushort* Bl, int* idsb, int tid)
{
    if (k < 128) {
        int dir = k >> 6, idx = k & 63;
        int m0 = (idx >> 4) * 64, n0 = (idx & 15) * 256;
        if (dir == 0)
            gemm64(0, m0, n0, enc_emb, input_ids, nullptr, enc_wih,
                   enc_bih, enc_bhh, nullptr, pre_enc, G4,
                   Ah, Al, Bh, Bl, idsb, tid);
        else
            gemm64(1, m0, n0, dec_emb, target_ids, nullptr, dec_wih,
                   dec_bih, dec_bhh, nullptr, pre_dec, G4,
                   Ah, Al, Bh, Bl, idsb, tid);
    }
    for (int j = k; j < 500; j += NWKR) {
        int m0 = (j / 125) * 64, n0 = (j % 125) * 256;
        gemm64(2, m0, n0, nullptr, nullptr, hs_mb, out_w, out_b, nullptr,
               outp, nullptr, VOC, Ah, Al, Bh, Bl, idsb, tid);
    }
}

// ===========================================================================
__global__ __launch_bounds__(THR, 2) void k_fused(
    const float* cond_emb, const float* enc_emb,
    const float* enc_wih, const float* enc_whh,
    const float* enc_bih, const float* enc_bhh,
    const float* mean_w, const float* mean_b,
    const float* lgv_w, const float* lgv_b,
    const float* l2h_w, const float* l2h_b,
    const float* l2c_w, const float* l2c_b,
    const float* dec_emb, const float* dec_wih, const float* dec_whh,
    const float* dec_bih, const float* dec_bhh,
    const float* out_w, const float* out_b, const float* eps,
    const int* input_ids, const int* target_ids,
    const int* p_ic, const int* p_tc,
    u64* pre_mb, u64* hs_mb, u64* mb, u64* zmb,
    float* outp, float* out_mlgv)
{
    __shared__ float  h_lds[8 * WCH];
    __shared__ float  red_s[32];
    __shared__ float  sm_s[8];
    __shared__ ushort AhS[64 * LDT];
    __shared__ ushort AlS[64 * LDT];
    __shared__ ushort BhS[256 * LDT];
    __shared__ ushort BlS[256 * LDT];
    __shared__ int    idsb_s[64];

    const int wg  = blockIdx.x;
    const int tid = threadIdx.x;
    u64* pre_enc = pre_mb;
    u64* pre_dec = pre_mb + (size_t)TT * G4;

    if (wg < NSEQ) {
        seq_role(cond_emb, enc_whh, mean_w, mean_b, lgv_w, lgv_b,
                 l2h_w, l2h_b, l2c_w, l2c_b, dec_whh, eps, p_ic, p_tc,
                 pre_enc, pre_dec, mb, zmb, hs_mb, out_mlgv,
                 h_lds, red_s, sm_s, wg, tid);
    } else {
        worker_role(wg - NSEQ, enc_emb, input_ids, enc_wih, enc_bih, enc_bhh,
                    dec_emb, target_ids, dec_wih, dec_bih, dec_bhh,
                    out_w, out_b, pre_enc, pre_dec, hs_mb, outp,
                    AhS, AlS, BhS, BlS, idsb_s, tid);
    }
}

// ---------------------------------------------------------------------------
extern "C" void kernel_launch(void* const* d_in, const int* in_sizes, int n_in,
                              void* d_out, int out_size, void* d_ws, size_t ws_size,
                              hipStream_t stream)
{
    const float* cond_emb = (const float*)d_in[0];
    const float* enc_emb  = (const float*)d_in[1];
    const float* enc_wih  = (const float*)d_in[2];
    const float* enc_whh  = (const float*)d_in[3];
    const float* enc_bih  = (const float*)d_in[4];
    const float* enc_bhh  = (const float*)d_in[5];
    const float* mean_w   = (const float*)d_in[6];
    const float* mean_b   = (const float*)d_in[7];
    const float* lgv_w    = (const float*)d_in[8];
    const float* lgv_b    = (const float*)d_in[9];
    const float* l2h_w    = (const float*)d_in[10];
    const float* l2h_b    = (const float*)d_in[11];
    const float* l2c_w    = (const float*)d_in[12];
    const float* l2c_b    = (const float*)d_in[13];
    const float* dec_emb  = (const float*)d_in[14];
    const float* dec_wih  = (const float*)d_in[15];
    const float* dec_whh  = (const float*)d_in[16];
    const float* dec_bih  = (const float*)d_in[17];
    const float* dec_bhh  = (const float*)d_in[18];
    const float* out_w    = (const float*)d_in[19];
    const float* out_b    = (const float*)d_in[20];
    const float* eps      = (const float*)d_in[21];
    const int* input_ids  = (const int*)d_in[22];
    const int* target_ids = (const int*)d_in[23];
    const int* p_ic       = (const int*)d_in[24];
    const int* p_tc       = (const int*)d_in[25];

    u64* pre_mb = (u64*)d_ws;                       // 2*TT*G4 entries (16 MB)
    u64* hs_mb  = pre_mb + (size_t)2 * TT * G4;     // TT*HD (2 MB)
    u64* mb     = hs_mb + (size_t)TT * HD;          // 2*HD
    u64* zmb    = mb + 2 * HD;                      // LAT

    float* outp     = (float*)d_out;
    float* out_mlgv = outp + (size_t)TT * VOC;

    size_t mb_total = ((size_t)2 * TT * G4 + (size_t)TT * HD + 2 * HD + LAT)
                      * sizeof(u64);
    hipMemsetAsync(pre_mb, 0, mb_total, stream);

    void* args[] = {
        (void*)&cond_emb, (void*)&enc_emb, (void*)&enc_wih, (void*)&enc_whh,
        (void*)&enc_bih, (void*)&enc_bhh, (void*)&mean_w, (void*)&mean_b,
        (void*)&lgv_w, (void*)&lgv_b, (void*)&l2h_w, (void*)&l2h_b,
        (void*)&l2c_w, (void*)&l2c_b, (void*)&dec_emb, (void*)&dec_wih,
        (void*)&dec_whh, (void*)&dec_bih, (void*)&dec_bhh, (void*)&out_w,
        (void*)&out_b, (void*)&eps, (void*)&input_ids, (void*)&target_ids,
        (void*)&p_ic, (void*)&p_tc, (void*)&pre_mb, (void*)&hs_mb,
        (void*)&mb, (void*)&zmb, (void*)&outp, (void*)&out_mlgv
    };
    hipLaunchCooperativeKernel((const void*)k_fused, dim3(NSEQ + NWKR),
                               dim3(THR), args, 0, stream);
}